// Round 2
// baseline (23665.910 us; speedup 1.0000x reference)
//
#include <hip/hip_runtime.h>
#include <hip/hip_bf16.h>
#include <math.h>

// GPT forward: B=8 T=1024 C=768 H=12 L=12 V=50304 D=64
#define BB 8
#define TT 1024
#define CC 768
#define HH 12
#define LL 12
#define VV 50304
#define DD 64

typedef __bf16 bf16;
typedef __bf16 bf16x8 __attribute__((ext_vector_type(8)));
typedef float f32x4 __attribute__((ext_vector_type(4)));

// ---------------- embedding: x[b,t,:] = lm_w[:, idx] + wpe[t,:] ----------------
__global__ __launch_bounds__(256) void k_embed(const int* __restrict__ idx,
                                               const float* __restrict__ lm_w,
                                               const float* __restrict__ wpe,
                                               float* __restrict__ x) {
  int bt = blockIdx.x;          // 0..B*T-1
  int t = bt % TT;
  int id = idx[bt];
  for (int c = threadIdx.x; c < CC; c += 256)
    x[(size_t)bt * CC + c] = lm_w[(size_t)c * VV + id] + wpe[(size_t)t * CC + c];
}

// ---------------- layernorm (center=False-style keras: mean-sub, scale, no beta) ----
__global__ __launch_bounds__(256) void k_ln(const float* __restrict__ x,
                                            const float* __restrict__ g,
                                            bf16* __restrict__ out) {
  __shared__ float red[8];
  int row = blockIdx.x;
  const float* xr = x + (size_t)row * CC;
  int tid = threadIdx.x;
  float v0 = xr[tid], v1 = xr[tid + 256], v2 = xr[tid + 512];
  float s = v0 + v1 + v2;
#pragma unroll
  for (int o = 1; o < 64; o <<= 1) s += __shfl_xor(s, o);
  if ((tid & 63) == 0) red[tid >> 6] = s;
  __syncthreads();
  float mean = (red[0] + red[1] + red[2] + red[3]) * (1.0f / CC);
  float d0 = v0 - mean, d1 = v1 - mean, d2 = v2 - mean;
  float q = d0 * d0 + d1 * d1 + d2 * d2;
#pragma unroll
  for (int o = 1; o < 64; o <<= 1) q += __shfl_xor(q, o);
  if ((tid & 63) == 0) red[4 + (tid >> 6)] = q;
  __syncthreads();
  float var = (red[4] + red[5] + red[6] + red[7]) * (1.0f / CC);
  float rs = rsqrtf(var + 1e-5f);
  bf16* op = out + (size_t)row * CC;
  op[tid]       = (bf16)(d0 * rs * g[tid]);
  op[tid + 256] = (bf16)(d1 * rs * g[tid + 256]);
  op[tid + 512] = (bf16)(d2 * rs * g[tid + 512]);
}

// final LN on last token of each batch -> compact f32 [B][C]
__global__ __launch_bounds__(256) void k_lnf(const float* __restrict__ x,
                                             const float* __restrict__ g,
                                             float* __restrict__ out) {
  __shared__ float red[8];
  int b = blockIdx.x;
  const float* xr = x + ((size_t)b * TT + (TT - 1)) * CC;
  int tid = threadIdx.x;
  float v0 = xr[tid], v1 = xr[tid + 256], v2 = xr[tid + 512];
  float s = v0 + v1 + v2;
#pragma unroll
  for (int o = 1; o < 64; o <<= 1) s += __shfl_xor(s, o);
  if ((tid & 63) == 0) red[tid >> 6] = s;
  __syncthreads();
  float mean = (red[0] + red[1] + red[2] + red[3]) * (1.0f / CC);
  float d0 = v0 - mean, d1 = v1 - mean, d2 = v2 - mean;
  float q = d0 * d0 + d1 * d1 + d2 * d2;
#pragma unroll
  for (int o = 1; o < 64; o <<= 1) q += __shfl_xor(q, o);
  if ((tid & 63) == 0) red[4 + (tid >> 6)] = q;
  __syncthreads();
  float var = (red[4] + red[5] + red[6] + red[7]) * (1.0f / CC);
  float rs = rsqrtf(var + 1e-5f);
  float* op = out + (size_t)b * CC;
  op[tid]       = d0 * rs * g[tid];
  op[tid + 256] = d1 * rs * g[tid + 256];
  op[tid + 512] = d2 * rs * g[tid + 512];
}

// ---------------- GEMM: C[M,N] = A(bf16)[M,K] @ W(f32)[K,N] + bias, fused epilogue --
// MODE 0: store bf16.  MODE 1: gelu(exact erf) -> bf16.  MODE 2: f32 residual x += .
template <int MODE>
__global__ __launch_bounds__(256) void k_gemm(const bf16* __restrict__ A,
                                              const float* __restrict__ W,
                                              const float* __restrict__ bias,
                                              bf16* __restrict__ Cb,
                                              float* __restrict__ Xres,
                                              int K, int N) {
  // LDS layout [kb][row][8] bf16: fragment read = ds_read_b128 of 8 contiguous k.
  __shared__ __align__(16) bf16 As[4][128][8];
  __shared__ __align__(16) bf16 Bs[4][128][8];
  int m0 = blockIdx.y * 128, n0 = blockIdx.x * 128;
  int tid = threadIdx.x;
  int lane = tid & 63, wid = tid >> 6;
  int wm = wid >> 1, wn = wid & 1;  // 2x2 waves, each 64x64
  f32x4 acc[4][4] = {};
  int arow = tid >> 2, aseg = tid & 3;  // A stage: 512 x bf16x8, 2/thread

  for (int k0 = 0; k0 < K; k0 += 32) {
    // stage A (bf16 -> straight copy)
#pragma unroll
    for (int i = 0; i < 2; i++) {
      int row = arow + i * 64;
      bf16x8 v = *(const bf16x8*)(A + (size_t)(m0 + row) * K + k0 + aseg * 8);
      *(bf16x8*)(&As[aseg][row][0]) = v;
    }
    // stage B (f32 -> bf16, transpose into [kb][n][e])
#pragma unroll
    for (int i = 0; i < 4; i++) {
      int f = tid + i * 256;          // 0..1023
      int k = f >> 5, c4 = f & 31;    // lanes along n: coalesced 512B
      f32x4 w = *(const f32x4*)(W + (size_t)(k0 + k) * N + n0 + c4 * 4);
      int kb = k >> 3, e = k & 7;
#pragma unroll
      for (int e2 = 0; e2 < 4; e2++) Bs[kb][c4 * 4 + e2][e] = (bf16)w[e2];
    }
    __syncthreads();
    int kb = lane >> 4, r = lane & 15;
    bf16x8 af[4], bfr[4];
#pragma unroll
    for (int i = 0; i < 4; i++) af[i] = *(const bf16x8*)(&As[kb][wm * 64 + i * 16 + r][0]);
#pragma unroll
    for (int j = 0; j < 4; j++) bfr[j] = *(const bf16x8*)(&Bs[kb][wn * 64 + j * 16 + r][0]);
#pragma unroll
    for (int i = 0; i < 4; i++)
#pragma unroll
      for (int j = 0; j < 4; j++)
        acc[i][j] = __builtin_amdgcn_mfma_f32_16x16x32_bf16(af[i], bfr[j], acc[i][j], 0, 0, 0);
    __syncthreads();
  }

  int rgrp = lane >> 4, cidx = lane & 15;
#pragma unroll
  for (int i = 0; i < 4; i++) {
#pragma unroll
    for (int j = 0; j < 4; j++) {
      int col = n0 + wn * 64 + j * 16 + cidx;
      float bcol = bias[col];
#pragma unroll
      for (int rr = 0; rr < 4; rr++) {
        int row = m0 + wm * 64 + i * 16 + rgrp * 4 + rr;
        float v = acc[i][j][rr] + bcol;
        if (MODE == 1) v = 0.5f * v * (1.0f + erff(v * 0.70710678118654752f));
        if (MODE == 2) {
          size_t o = (size_t)row * N + col;
          Xres[o] = Xres[o] + v;
        } else {
          Cb[(size_t)row * N + col] = (bf16)v;
        }
      }
    }
  }
}

// ---------------- flash attention (VALU), 1 thread per q-row, 64-key LDS tiles -----
__global__ __launch_bounds__(128) void k_attn(const bf16* __restrict__ qkv,
                                              bf16* __restrict__ att) {
  __shared__ __align__(16) bf16 Ks[64][DD];
  __shared__ __align__(16) bf16 Vs[64][DD];
  __shared__ float Ss[128][17];  // padded: bank-conflict-free per-lane rows
  int qt = blockIdx.x;          // 0..7
  int bh = blockIdx.y;          // 0..95
  int b = bh / HH, h = bh % HH;
  int tid = threadIdx.x;
  int qg = qt * 128 + tid;

  float q[DD], o[DD];
  {
    const bf16* qp = qkv + ((size_t)(b * TT + qg)) * (3 * CC) + h * DD;
#pragma unroll
    for (int s8 = 0; s8 < 8; s8++) {
      bf16x8 v = *(const bf16x8*)(qp + s8 * 8);
#pragma unroll
      for (int e = 0; e < 8; e++) q[s8 * 8 + e] = (float)v[e];
    }
  }
#pragma unroll
  for (int d = 0; d < DD; d++) o[d] = 0.0f;
  float mrun = -1e30f, lrun = 0.0f;

  int ktmax = qt * 2 + 1;
  for (int kt = 0; kt <= ktmax; kt++) {
    // stage K,V tile (64x64 bf16 each), straight bf16 copies
#pragma unroll
    for (int i = 0; i < 4; i++) {
      int f = tid + i * 128;  // 0..511
      int row = f >> 3, seg = f & 7;
      size_t g = ((size_t)(b * TT + kt * 64 + row)) * (3 * CC) + h * DD + seg * 8;
      *(bf16x8*)(&Ks[row][seg * 8]) = *(const bf16x8*)(qkv + g + CC);
      *(bf16x8*)(&Vs[row][seg * 8]) = *(const bf16x8*)(qkv + g + 2 * CC);
    }
    __syncthreads();
    if (qg >= kt * 64) {
#pragma unroll 1
      for (int sub = 0; sub < 4; sub++) {
        int kbase = kt * 64 + sub * 16;
        if (kbase > qg) break;
        // scores for 16 keys
#pragma unroll 2
        for (int j = 0; j < 16; j++) {
          int key = kbase + j;
          float s;
          if (key > qg) {
            s = -1e30f;
          } else {
            s = 0.0f;
#pragma unroll
            for (int seg = 0; seg < 8; seg++) {
              bf16x8 kv = *(const bf16x8*)(&Ks[sub * 16 + j][seg * 8]);
#pragma unroll
              for (int e = 0; e < 8; e++) s += q[seg * 8 + e] * (float)kv[e];
            }
            s *= 0.125f;
          }
          Ss[tid][j] = s;
        }
        float tm = -1e30f;
#pragma unroll
        for (int j = 0; j < 16; j++) tm = fmaxf(tm, Ss[tid][j]);
        float mnew = fmaxf(mrun, tm);
        float scale = __expf(mrun - mnew);
        lrun *= scale;
#pragma unroll
        for (int d = 0; d < DD; d++) o[d] *= scale;
#pragma unroll 2
        for (int j = 0; j < 16; j++) {
          float p = __expf(Ss[tid][j] - mnew);
          lrun += p;
#pragma unroll
          for (int seg = 0; seg < 8; seg++) {
            bf16x8 vv = *(const bf16x8*)(&Vs[sub * 16 + j][seg * 8]);
#pragma unroll
            for (int e = 0; e < 8; e++) o[seg * 8 + e] += p * (float)vv[e];
          }
        }
        mrun = mnew;
      }
    }
    __syncthreads();
  }
  float inv = 1.0f / lrun;
  bf16* op = att + ((size_t)(b * TT + qg)) * CC + h * DD;
#pragma unroll
  for (int d = 0; d < DD; d++) op[d] = (bf16)(o[d] * inv);
}

// ---------------- logits: out[b,v] = sum_c xl[b,c] * lm_w[c,v]  (f32) --------------
__global__ __launch_bounds__(128) void k_logits(const float* __restrict__ xl,
                                                const float* __restrict__ lm_w,
                                                float* __restrict__ out) {
  __shared__ float xs[BB * CC];
  for (int i = threadIdx.x; i < BB * CC; i += 128) xs[i] = xl[i];
  __syncthreads();
  int v = blockIdx.x * 128 + threadIdx.x;  // V = 393*128 exactly
  float acc[BB];
#pragma unroll
  for (int b = 0; b < BB; b++) acc[b] = 0.0f;
  for (int c = 0; c < CC; c++) {
    float w = lm_w[(size_t)c * VV + v];
#pragma unroll
    for (int b = 0; b < BB; b++) acc[b] += xs[b * CC + c] * w;
  }
#pragma unroll
  for (int b = 0; b < BB; b++) out[(size_t)b * VV + v] = acc[b];
}

// ---------------- host ----------------
extern "C" void kernel_launch(void* const* d_in, const int* in_sizes, int n_in,
                              void* d_out, int out_size, void* d_ws, size_t ws_size,
                              hipStream_t stream) {
  const int*   idx     = (const int*)d_in[0];
  const float* lm_w    = (const float*)d_in[1];
  const float* wpe     = (const float*)d_in[2];
  const float* attn_w  = (const float*)d_in[3];
  const float* attn_b  = (const float*)d_in[4];
  const float* proj_w  = (const float*)d_in[5];
  const float* proj_b  = (const float*)d_in[6];
  const float* ln1_g   = (const float*)d_in[7];
  const float* ln2_g   = (const float*)d_in[8];
  const float* fc_w    = (const float*)d_in[9];
  const float* fc_b    = (const float*)d_in[10];
  const float* mproj_w = (const float*)d_in[11];
  const float* mproj_b = (const float*)d_in[12];
  const float* lnf_g   = (const float*)d_in[13];
  float* out = (float*)d_out;

  // ws layout (total ~96 MB): x f32 | xn bf16 | att bf16 | big (qkv / mlp-hidden bf16)
  char* ws = (char*)d_ws;
  float* x   = (float*)ws;                                   // 25,165,824 B
  bf16*  xn  = (bf16*)(ws + 25165824);                       // 12,582,912 B
  bf16*  att = (bf16*)(ws + 25165824 + 12582912);            // 12,582,912 B
  bf16*  big = (bf16*)(ws + 50331648);                       // 50,331,648 B
  bf16*  qkv = big;
  bf16*  hb  = big;
  float* xl  = (float*)xn;  // reuse xn region for final-LN output [8,768] f32

  k_embed<<<dim3(BB * TT), dim3(256), 0, stream>>>(idx, lm_w, wpe, x);

  for (int l = 0; l < LL; l++) {
    k_ln<<<dim3(BB * TT), dim3(256), 0, stream>>>(x, ln1_g + (size_t)l * CC, xn);
    k_gemm<0><<<dim3(3 * CC / 128, BB * TT / 128), dim3(256), 0, stream>>>(
        xn, attn_w + (size_t)l * CC * 3 * CC, attn_b + (size_t)l * 3 * CC,
        qkv, nullptr, CC, 3 * CC);
    k_attn<<<dim3(TT / 128, BB * HH), dim3(128), 0, stream>>>(qkv, att);
    k_gemm<2><<<dim3(CC / 128, BB * TT / 128), dim3(256), 0, stream>>>(
        att, proj_w + (size_t)l * CC * CC, proj_b + (size_t)l * CC,
        nullptr, x, CC, CC);
    k_ln<<<dim3(BB * TT), dim3(256), 0, stream>>>(x, ln2_g + (size_t)l * CC, xn);
    k_gemm<1><<<dim3(4 * CC / 128, BB * TT / 128), dim3(256), 0, stream>>>(
        xn, fc_w + (size_t)l * CC * 4 * CC, fc_b + (size_t)l * 4 * CC,
        hb, nullptr, CC, 4 * CC);
    k_gemm<2><<<dim3(CC / 128, BB * TT / 128), dim3(256), 0, stream>>>(
        hb, mproj_w + (size_t)l * 4 * CC * CC, mproj_b + (size_t)l * CC,
        nullptr, x, 4 * CC, CC);
  }

  k_lnf<<<dim3(BB), dim3(256), 0, stream>>>(x, lnf_g, xl);
  k_logits<<<dim3(VV / 128), dim3(128), 0, stream>>>(xl, lm_w, out);
}